// Round 2
// baseline (130.113 us; speedup 1.0000x reference)
//
#include <hip/hip_runtime.h>

#define B_SZ 8192
#define C_SZ 1024
#define NCLS 100
#define INV_T 0.25f
#define MAX_ITEMS 65536

typedef unsigned int uint32;

using bf16x8 = __attribute__((ext_vector_type(8))) short;
using f32x16 = __attribute__((ext_vector_type(16))) float;

// round-to-nearest-even fp32 -> bf16 (inputs are positive, finite)
__device__ __forceinline__ unsigned short f2bf(float f) {
    uint32 u = __float_as_uint(f);
    u = u + 0x7fffu + ((u >> 16) & 1u);
    return (unsigned short)(u >> 16);
}

// Block 0: prep (zero accum/done, bucket rows by label via LDS atomics, build the
// 32x32-tile item table). Blocks 1..B_SZ: row softmax(x/T)+1e-8 -> bf16 probs and
// t[row] = mean(p*log p). Prep is independent of the row work and hides under it.
__global__ __launch_bounds__(256) void softmax_prep_kernel(
        const float* __restrict__ x, const int* __restrict__ target,
        uint32* __restrict__ probs_bf, float* __restrict__ t,
        int* __restrict__ counts, int* __restrict__ lists,
        int* __restrict__ items, int* __restrict__ nitems,
        float* __restrict__ accum, int* __restrict__ done_ctr) {
    int tid = threadIdx.x;

    if (blockIdx.x == 0) {
        __shared__ int cnt[NCLS];
        __shared__ int tbase[NCLS];
        if (tid < NCLS) cnt[tid] = 0;
        if (tid == 0) { accum[0] = 0.0f; done_ctr[0] = 0; }
        __syncthreads();
        #pragma unroll 4
        for (int i = 0; i < B_SZ / 256; i++) {
            int r = i * 256 + tid;
            int lbl = target[r];
            if (lbl < 0) lbl = 0;
            if (lbl >= NCLS) lbl = NCLS - 1;   // defensive: keep in-bounds
            int slot = atomicAdd(&cnt[lbl], 1);
            lists[lbl * B_SZ + slot] = r;
        }
        __syncthreads();
        if (tid < NCLS) counts[tid] = cnt[tid];
        if (tid == 0) {
            int tot = 0;
            for (int k = 0; k < NCLS; k++) {
                int nt = (cnt[k] + 31) >> 5;
                tbase[k] = tot;
                tot += nt * nt;
            }
            nitems[0] = tot;
        }
        __syncthreads();
        if (tid < NCLS) {
            int nt = (cnt[tid] + 31) >> 5;
            int base = tbase[tid];
            int z = 0;
            for (int a = 0; a < nt; a++)
                for (int b = 0; b < nt; b++)
                    items[base + z++] = tid | (a << 8) | (b << 20);
        }
        return;
    }

    int row = blockIdx.x - 1;
    const float4* xr = (const float4*)(x + (size_t)row * C_SZ);
    float4 v = xr[tid];
    v.x *= INV_T; v.y *= INV_T; v.z *= INV_T; v.w *= INV_T;

    __shared__ float red[12];
    int wid = tid >> 6;

    float m = fmaxf(fmaxf(v.x, v.y), fmaxf(v.z, v.w));
    #pragma unroll
    for (int o = 32; o >= 1; o >>= 1) m = fmaxf(m, __shfl_xor(m, o, 64));
    if ((tid & 63) == 0) red[wid] = m;
    __syncthreads();
    m = fmaxf(fmaxf(red[0], red[1]), fmaxf(red[2], red[3]));

    float4 e;
    e.x = __expf(v.x - m); e.y = __expf(v.y - m);
    e.z = __expf(v.z - m); e.w = __expf(v.w - m);
    float s = (e.x + e.y) + (e.z + e.w);
    #pragma unroll
    for (int o = 32; o >= 1; o >>= 1) s += __shfl_xor(s, o, 64);
    if ((tid & 63) == 0) red[4 + wid] = s;
    __syncthreads();
    float Z = (red[4] + red[5]) + (red[6] + red[7]);
    float rZ = 1.0f / Z;

    float4 p;
    p.x = e.x * rZ + 1e-8f; p.y = e.y * rZ + 1e-8f;
    p.z = e.z * rZ + 1e-8f; p.w = e.w * rZ + 1e-8f;

    uint2 packed;
    packed.x = ((uint32)f2bf(p.y) << 16) | (uint32)f2bf(p.x);
    packed.y = ((uint32)f2bf(p.w) << 16) | (uint32)f2bf(p.z);
    ((uint2*)(probs_bf + (size_t)row * (C_SZ / 2)))[tid] = packed;

    float pl = p.x * __logf(p.x) + p.y * __logf(p.y) +
               p.z * __logf(p.z) + p.w * __logf(p.w);
    #pragma unroll
    for (int o = 32; o >= 1; o >>= 1) pl += __shfl_xor(pl, o, 64);
    if ((tid & 63) == 0) red[8 + wid] = pl;
    __syncthreads();
    if (tid == 0)
        t[row] = ((red[8] + red[9]) + (red[10] + red[11])) * (1.0f / C_SZ);
}

// One wave per 32x32 output tile. mfma_f32_32x32x16_bf16 A/B fragment layout
// (lane l: row l&31, k = (l>>5)*8 + j, 8 contiguous bf16) is exactly one 16B
// global load per lane -> load fragments straight from L2/L3-resident probs,
// no LDS, no barriers. Full K unroll: 128 loads (imm offsets 0..2032) + 64 MFMA,
// compiler pipelines to register budget. Finalize fused via done-counter.
__global__ __launch_bounds__(64) void pair_kernel(
        const char* __restrict__ probs, const float* __restrict__ t,
        const int* __restrict__ counts, const int* __restrict__ lists,
        const int* __restrict__ nitems, const int* __restrict__ items,
        float* __restrict__ accum, int* __restrict__ done_ctr,
        float* __restrict__ out) {
    int tid = threadIdx.x;
    int l = tid & 31;
    int h = tid >> 5;
    int NI = nitems[0];
    if (NI > MAX_ITEMS) NI = MAX_ITEMS;          // defensive: never walk garbage
    float lacc = 0.0f;

    for (int it = blockIdx.x; it < NI; it += (int)gridDim.x) {
        int pk = items[it];
        int k = pk & 255;
        if (k >= NCLS) continue;                 // defensive
        int ti = (pk >> 8) & 0xfff;
        int tj = pk >> 20;
        int m = counts[k];
        if (m < 1) continue;                     // defensive
        if (m > B_SZ) m = B_SZ;

        int ia = ti * 32 + l; if (ia > m - 1) ia = m - 1;   // clamp; masked below
        int ja = tj * 32 + l; if (ja > m - 1) ja = m - 1;
        int ra = lists[k * B_SZ + ia] & (B_SZ - 1);          // defensive mask
        int rb = lists[k * B_SZ + ja] & (B_SZ - 1);
        const char* rowA = probs + (size_t)ra * (C_SZ * 2) + h * 16;
        const char* rowB = probs + (size_t)rb * (C_SZ * 2) + h * 16;
        float tjv = t[rb];

        f32x16 acc = {};
        #pragma unroll
        for (int kk = 0; kk < 64; kk++) {
            bf16x8 a = *(const bf16x8*)(rowA + kk * 32);
            bf16x8 b = *(const bf16x8*)(rowB + kk * 32);
            acc = __builtin_amdgcn_mfma_f32_32x32x16_bf16(a, b, acc, 0, 0, 0);
        }

        // D layout: col = lane&31 (B/tj side), row = (g&3)+8*(g>>2)+4*h (A/ti side)
        int jl = tj * 32 + l;
        bool jv = jl < m;
        float local = 0.0f;
        #pragma unroll
        for (int g = 0; g < 16; g++) {
            int rowloc = (g & 3) + 8 * (g >> 2) + 4 * h;
            int il = ti * 32 + rowloc;
            if (jv && il < m && il != jl) {
                float kl = tjv - acc[g] * (1.0f / C_SZ);
                local += kl * kl;
            }
        }
        lacc += local;
    }

    #pragma unroll
    for (int o = 32; o >= 1; o >>= 1) lacc += __shfl_xor(lacc, o, 64);
    if (tid == 0) {
        atomicAdd(accum, lacc);
        __threadfence();
        if (atomicAdd(done_ctr, 1) == (int)gridDim.x - 1) {
            __threadfence();
            out[0] = atomicAdd(accum, 0.0f) * (1.0f / B_SZ);
        }
    }
}

extern "C" void kernel_launch(void* const* d_in, const int* in_sizes, int n_in,
                              void* d_out, int out_size, void* d_ws, size_t ws_size,
                              hipStream_t stream) {
    const float* x = (const float*)d_in[0];
    const int* target = (const int*)d_in[1];
    float* out = (float*)d_out;

    char* ws = (char*)d_ws;
    uint32* probs_bf = (uint32*)ws;                                   // 16 MB (B*C bf16)
    char* p = ws + (size_t)B_SZ * C_SZ * 2;
    float* t = (float*)p;            p += B_SZ * 4;                   // 32 KB
    int* counts = (int*)p;           p += 128 * 4;                    // 512 B
    int* nitems = (int*)p;           p += 16;                         // 4 B (+pad)
    int* lists = (int*)p;            p += (size_t)NCLS * B_SZ * 4;    // 3.2 MB
    int* items = (int*)p;            p += MAX_ITEMS * 4;              // 256 KB
    float* accum = (float*)p;        p += 16;                         // 4 B (+pad)
    int* done_ctr = (int*)p;                                          // 4 B

    softmax_prep_kernel<<<B_SZ + 1, 256, 0, stream>>>(x, target, probs_bf, t,
                                                      counts, lists, items, nitems,
                                                      accum, done_ctr);
    pair_kernel<<<1024, 64, 0, stream>>>((const char*)probs_bf, t, counts, lists,
                                         nitems, items, accum, done_ctr, out);
}

// Round 3
// 129.489 us; speedup vs baseline: 1.0048x; 1.0048x over previous
//
#include <hip/hip_runtime.h>

#define B_SZ 8192
#define C_SZ 1024
#define NCLS 100
#define INV_T 0.25f
#define MAX_ITEMS 65536

typedef unsigned int uint32;

using bf16x8 = __attribute__((ext_vector_type(8))) short;
using f32x16 = __attribute__((ext_vector_type(16))) float;

// round-to-nearest-even fp32 -> bf16 (inputs are positive, finite)
__device__ __forceinline__ unsigned short f2bf(float f) {
    uint32 u = __float_as_uint(f);
    u = u + 0x7fffu + ((u >> 16) & 1u);
    return (unsigned short)(u >> 16);
}

// Block 0: prep (zero accum/done, bucket rows by label via LDS atomics, build the
// 32x32-tile item table). Blocks 1..B_SZ: row softmax(x/T)+1e-8 -> bf16 probs and
// t[row] = mean(p*log p). Prep is independent of the row work and hides under it.
__global__ __launch_bounds__(256) void softmax_prep_kernel(
        const float* __restrict__ x, const int* __restrict__ target,
        uint32* __restrict__ probs_bf, float* __restrict__ t,
        int* __restrict__ counts, int* __restrict__ lists,
        int* __restrict__ items, int* __restrict__ nitems,
        float* __restrict__ accum, int* __restrict__ done_ctr) {
    int tid = threadIdx.x;

    if (blockIdx.x == 0) {
        __shared__ int cnt[NCLS];
        __shared__ int tbase[NCLS];
        if (tid < NCLS) cnt[tid] = 0;
        if (tid == 0) { accum[0] = 0.0f; done_ctr[0] = 0; }
        __syncthreads();
        #pragma unroll 4
        for (int i = 0; i < B_SZ / 256; i++) {
            int r = i * 256 + tid;
            int lbl = target[r];
            if (lbl < 0) lbl = 0;
            if (lbl >= NCLS) lbl = NCLS - 1;   // defensive: keep in-bounds
            int slot = atomicAdd(&cnt[lbl], 1);
            lists[lbl * B_SZ + slot] = r;
        }
        __syncthreads();
        if (tid < NCLS) counts[tid] = cnt[tid];
        if (tid == 0) {
            int tot = 0;
            for (int k = 0; k < NCLS; k++) {
                int nt = (cnt[k] + 31) >> 5;
                tbase[k] = tot;
                tot += nt * nt;
            }
            nitems[0] = tot;
        }
        __syncthreads();
        if (tid < NCLS) {
            int nt = (cnt[tid] + 31) >> 5;
            int base = tbase[tid];
            int z = 0;
            for (int a = 0; a < nt; a++)
                for (int b = 0; b < nt; b++)
                    items[base + z++] = tid | (a << 8) | (b << 20);
        }
        return;
    }

    int row = blockIdx.x - 1;
    const float4* xr = (const float4*)(x + (size_t)row * C_SZ);
    float4 v = xr[tid];
    v.x *= INV_T; v.y *= INV_T; v.z *= INV_T; v.w *= INV_T;

    __shared__ float red[12];
    int wid = tid >> 6;

    float m = fmaxf(fmaxf(v.x, v.y), fmaxf(v.z, v.w));
    #pragma unroll
    for (int o = 32; o >= 1; o >>= 1) m = fmaxf(m, __shfl_xor(m, o, 64));
    if ((tid & 63) == 0) red[wid] = m;
    __syncthreads();
    m = fmaxf(fmaxf(red[0], red[1]), fmaxf(red[2], red[3]));

    float4 e;
    e.x = __expf(v.x - m); e.y = __expf(v.y - m);
    e.z = __expf(v.z - m); e.w = __expf(v.w - m);
    float s = (e.x + e.y) + (e.z + e.w);
    #pragma unroll
    for (int o = 32; o >= 1; o >>= 1) s += __shfl_xor(s, o, 64);
    if ((tid & 63) == 0) red[4 + wid] = s;
    __syncthreads();
    float Z = (red[4] + red[5]) + (red[6] + red[7]);
    float rZ = 1.0f / Z;

    float4 p;
    p.x = e.x * rZ + 1e-8f; p.y = e.y * rZ + 1e-8f;
    p.z = e.z * rZ + 1e-8f; p.w = e.w * rZ + 1e-8f;

    uint2 packed;
    packed.x = ((uint32)f2bf(p.y) << 16) | (uint32)f2bf(p.x);
    packed.y = ((uint32)f2bf(p.w) << 16) | (uint32)f2bf(p.z);
    ((uint2*)(probs_bf + (size_t)row * (C_SZ / 2)))[tid] = packed;

    float pl = p.x * __logf(p.x) + p.y * __logf(p.y) +
               p.z * __logf(p.z) + p.w * __logf(p.w);
    #pragma unroll
    for (int o = 32; o >= 1; o >>= 1) pl += __shfl_xor(pl, o, 64);
    if ((tid & 63) == 0) red[8 + wid] = pl;
    __syncthreads();
    if (tid == 0)
        t[row] = ((red[8] + red[9]) + (red[10] + red[11])) * (1.0f / C_SZ);
}

// One wave per 32x32 output tile. mfma_f32_32x32x16_bf16 A/B fragment layout
// (lane l: row l&31, k = (l>>5)*8 + j, 8 contiguous bf16) is exactly one 16B
// global load per lane -> load fragments straight from L2/L3-resident probs,
// no LDS, no barriers. Full K unroll: 128 loads (imm offsets 0..2032) + 64 MFMA.
// __launch_bounds__(64, 1): round-2 showed the default bound capped VGPRs at 56,
// serializing the 128 loads (51.5us = 128 x ~950cyc). Freeing the allocator lets
// the compiler keep ~20 loads in flight; this kernel lives on ILP, not occupancy
// (only ~900 waves exist -> ~3.5 waves/CU regardless).
__global__ __launch_bounds__(64, 1) void pair_kernel(
        const char* __restrict__ probs, const float* __restrict__ t,
        const int* __restrict__ counts, const int* __restrict__ lists,
        const int* __restrict__ nitems, const int* __restrict__ items,
        float* __restrict__ accum, int* __restrict__ done_ctr,
        float* __restrict__ out) {
    int tid = threadIdx.x;
    int l = tid & 31;
    int h = tid >> 5;
    int NI = nitems[0];
    if (NI > MAX_ITEMS) NI = MAX_ITEMS;          // defensive: never walk garbage
    float lacc = 0.0f;

    for (int it = blockIdx.x; it < NI; it += (int)gridDim.x) {
        int pk = items[it];
        int k = pk & 255;
        if (k >= NCLS) continue;                 // defensive
        int ti = (pk >> 8) & 0xfff;
        int tj = pk >> 20;
        int m = counts[k];
        if (m < 1) continue;                     // defensive
        if (m > B_SZ) m = B_SZ;

        int ia = ti * 32 + l; if (ia > m - 1) ia = m - 1;   // clamp; masked below
        int ja = tj * 32 + l; if (ja > m - 1) ja = m - 1;
        int ra = lists[k * B_SZ + ia] & (B_SZ - 1);          // defensive mask
        int rb = lists[k * B_SZ + ja] & (B_SZ - 1);
        const char* rowA = probs + (size_t)ra * (C_SZ * 2) + h * 16;
        const char* rowB = probs + (size_t)rb * (C_SZ * 2) + h * 16;
        float tjv = t[rb];

        f32x16 acc = {};
        #pragma unroll
        for (int kk = 0; kk < 64; kk++) {
            bf16x8 a = *(const bf16x8*)(rowA + kk * 32);
            bf16x8 b = *(const bf16x8*)(rowB + kk * 32);
            acc = __builtin_amdgcn_mfma_f32_32x32x16_bf16(a, b, acc, 0, 0, 0);
        }

        // D layout: col = lane&31 (B/tj side), row = (g&3)+8*(g>>2)+4*h (A/ti side)
        int jl = tj * 32 + l;
        bool jv = jl < m;
        float local = 0.0f;
        #pragma unroll
        for (int g = 0; g < 16; g++) {
            int rowloc = (g & 3) + 8 * (g >> 2) + 4 * h;
            int il = ti * 32 + rowloc;
            if (jv && il < m && il != jl) {
                float kl = tjv - acc[g] * (1.0f / C_SZ);
                local += kl * kl;
            }
        }
        lacc += local;
    }

    #pragma unroll
    for (int o = 32; o >= 1; o >>= 1) lacc += __shfl_xor(lacc, o, 64);
    if (tid == 0) {
        atomicAdd(accum, lacc);
        __threadfence();
        if (atomicAdd(done_ctr, 1) == (int)gridDim.x - 1) {
            __threadfence();
            out[0] = atomicAdd(accum, 0.0f) * (1.0f / B_SZ);
        }
    }
}

extern "C" void kernel_launch(void* const* d_in, const int* in_sizes, int n_in,
                              void* d_out, int out_size, void* d_ws, size_t ws_size,
                              hipStream_t stream) {
    const float* x = (const float*)d_in[0];
    const int* target = (const int*)d_in[1];
    float* out = (float*)d_out;

    char* ws = (char*)d_ws;
    uint32* probs_bf = (uint32*)ws;                                   // 16 MB (B*C bf16)
    char* p = ws + (size_t)B_SZ * C_SZ * 2;
    float* t = (float*)p;            p += B_SZ * 4;                   // 32 KB
    int* counts = (int*)p;           p += 128 * 4;                    // 512 B
    int* nitems = (int*)p;           p += 16;                         // 4 B (+pad)
    int* lists = (int*)p;            p += (size_t)NCLS * B_SZ * 4;    // 3.2 MB
    int* items = (int*)p;            p += MAX_ITEMS * 4;              // 256 KB
    float* accum = (float*)p;        p += 16;                         // 4 B (+pad)
    int* done_ctr = (int*)p;                                          // 4 B

    softmax_prep_kernel<<<B_SZ + 1, 256, 0, stream>>>(x, target, probs_bf, t,
                                                      counts, lists, items, nitems,
                                                      accum, done_ctr);
    pair_kernel<<<1024, 64, 0, stream>>>((const char*)probs_bf, t, counts, lists,
                                         nitems, items, accum, done_ctr, out);
}